// Round 10
// baseline (460.617 us; speedup 1.0000x reference)
//
#include <hip/hip_runtime.h>
#include <stdint.h>

#define NODES  50000
#define MPAD   50048      // 391 * 128
#define NGRAPH 8
#define NP_G   6250
#define EPG    100000
#define EDGES  800000
#define KKEEP  5000
#define HID    256
#define CIN    512
#define H3     768
#define SCANB  196        // 196*256 = 50176 >= NODES
#define RCHUNK 200        // KKEEP / 25
#define MLPCH  24         // layer-1 k-chunks
#define MLPCK  64         // 1536 / 24
#define ESL    3125       // edges per slice (EPG/32); also NP_G/2 bucket-half

// K1 block ranges: hist, cast_W1, cast_W2, pwnorm (x-cast fused into k2 GEMM1)
#define K1_HIST  512
#define K1_W1    512
#define K1_W2    256
#define K1_TOTAL (K1_HIST + K1_W1 + K1_W2 + 1)
// gemm grid: 64x128 tiles, graph-pinned (blockIdx%8 == owner graph of row-tile).
#define GEMM_GRID 1568
#define FILL_GRID 256     // 8 graphs * 32 slices
#define K2_TOTAL  (GEMM_GRID + FILL_GRID)

using f32x4  = __attribute__((ext_vector_type(4))) float;
using bf16x8 = __attribute__((ext_vector_type(8))) short;
using u16x8  = __attribute__((ext_vector_type(8))) unsigned short;
typedef unsigned short u16;
typedef unsigned int   u32;
typedef unsigned long long u64;

__device__ __forceinline__ float bf2f(u16 u) {
    return __uint_as_float(((uint32_t)u) << 16);
}
__device__ __forceinline__ u16 f2bf(float f) {     // RNE
    uint32_t u = __float_as_uint(f);
    u += 0x7fffu + ((u >> 16) & 1u);
    return (u16)(u >> 16);
}
// 8 x f32 -> 8 x bf16 (RNE) via v_cvt_pk_bf16_f32; layout matches the scalar
// f2bf ushort4 pack (lo=first elem) — verified bit-exact end-to-end in R3.
__device__ __forceinline__ int4 f32x8_to_bf16x8(float4 a, float4 b) {
    int4 r;
    asm("v_cvt_pk_bf16_f32 %0, %1, %2" : "=v"(r.x) : "v"(a.x), "v"(a.y));
    asm("v_cvt_pk_bf16_f32 %0, %1, %2" : "=v"(r.y) : "v"(a.z), "v"(a.w));
    asm("v_cvt_pk_bf16_f32 %0, %1, %2" : "=v"(r.z) : "v"(b.x), "v"(b.y));
    asm("v_cvt_pk_bf16_f32 %0, %1, %2" : "=v"(r.w) : "v"(b.z), "v"(b.w));
    return r;
}

// ---------------- K1: LDS edge histograms + W casts + pwnorm ---------------------
__global__ __launch_bounds__(256) void k1_kernel(
        const int* __restrict__ ei, const float* __restrict__ ew,
        u64* __restrict__ partial,
        const float* __restrict__ W1, const float* __restrict__ W2,
        const float* __restrict__ pw,
        u16* __restrict__ Wt1, u16* __restrict__ Wt2, float* __restrict__ invn) {
    __shared__ __align__(16) char smem[ESL * 8];   // 25000 B
    int b = blockIdx.x, t = threadIdx.x;
    if (b < K1_HIST) {
        u64* hl = (u64*)smem;                       // 3125 buckets (one half)
        int g  = b >> 6;
        int r  = b & 63;
        int bb = r >> 1;                            // edge slice 0..31
        int h  = r & 1;                             // bucket half
        for (int k = t; k < ESL; k += 256) hl[k] = 0ull;
        __syncthreads();
        int ebase = g * EPG + bb * ESL;
        int lo = h * ESL;
        for (int k = t; k < ESL; k += 256) {
            int e = ebase + k;
            int d = ei[EDGES + e];
            int il = d - g * NP_G - lo;
            if ((unsigned)il < (unsigned)ESL) {
                u64 enc = (1ull << 48) | (u64)(ew[e] * 4294967296.0f);
                atomicAdd(&hl[il], enc);            // LDS atomic
            }
        }
        __syncthreads();
        u64* prow = partial + (size_t)(g * 32 + bb) * NP_G + lo;
        for (int k = t; k < ESL; k += 256) prow[k] = hl[k];
    } else if (b < K1_HIST + K1_W1) {               // Wt1[n*512+k] = W1[k*256+n]
        int id = (b - K1_HIST) * 256 + t;
        int n = id >> 9, k = id & 511;
        Wt1[id] = f2bf(W1[(size_t)k * HID + n]);
    } else if (b < K1_TOTAL - 1) {                  // Wt2[n*256+k] = W2[k*256+n]
        int id = (b - K1_HIST - K1_W1) * 256 + t;
        int n = id >> 8, k = id & 255;
        Wt2[id] = f2bf(W2[(size_t)k * HID + n]);
    } else {                                        // pwnorm
        float* sh = (float*)smem;
        float s = 0.f;
        for (int i = t; i < H3; i += 256) { float v = pw[i]; s += v * v; }
        sh[t] = s; __syncthreads();
        for (int off = 128; off; off >>= 1) {
            if (t < off) sh[t] += sh[t + off];
            __syncthreads();
        }
        if (t == 0) invn[0] = rsqrtf(sh[0]);
    }
}

// ---- scan1 v2: reduce 32 partials/node -> count + deg; emit per-block prefixes ---
__global__ void scan1_kernel(const u64* __restrict__ partial,
                             u32* __restrict__ blockbase,
                             int* __restrict__ iscan, int* __restrict__ bsum,
                             float* __restrict__ dinv) {
    int b = blockIdx.x, t = threadIdx.x;
    int i = b * 256 + t;
    int c = 0;
    if (i < NODES) {
        int g = i / NP_G, il = i - g * NP_G;
        size_t base = (size_t)(g * 32) * NP_G + il;
        u64 fix = 0ull; u32 cnt = 0;
#pragma unroll 4
        for (int j = 0; j < 32; ++j) {
            size_t idx = base + (size_t)j * NP_G;
            u64 pv = partial[idx];
            blockbase[idx] = cnt;                 // exclusive prefix over blocks
            cnt += (u32)(pv >> 48);
            fix += pv & 0xFFFFFFFFFFFFull;
        }
        c = (int)cnt;
        float deg = (float)fix * (1.0f / 4294967296.0f);
        dinv[i] = rsqrtf(deg + 1.0f);
    }
    int lane = t & 63, wv = t >> 6;
    int v = c;
    for (int off = 1; off < 64; off <<= 1) {
        int u = __shfl_up(v, off);
        if (lane >= off) v += u;
    }
    __shared__ int ws[4];
    if (lane == 63) ws[wv] = v;
    __syncthreads();
    if (t == 0) { int s = 0; for (int k = 0; k < 4; k++) { int tmp = ws[k]; ws[k] = s; s += tmp; } }
    __syncthreads();
    v += ws[wv];
    if (i < NODES) iscan[i] = v - c;              // block-local EXCLUSIVE scan
    if (t == 255) bsum[b] = v;
}

// scan3 (scan2 fused): each block reduces bsum[0..b-1] itself, then adds iscan.
__global__ void scan3_kernel(const int* __restrict__ iscan, const int* __restrict__ bsum,
                             int* __restrict__ rowptr) {
    int b = blockIdx.x, t = threadIdx.x;
    int v = (t < b) ? bsum[t] : 0;                // b <= 196 < 256, no SCANB overrun
    for (int off = 1; off < 64; off <<= 1) v += __shfl_xor(v, off, 64);
    __shared__ int ws[4];
    if ((t & 63) == 0) ws[t >> 6] = v;
    __syncthreads();
    int boffb = ws[0] + ws[1] + ws[2] + ws[3];
    int i = b * 256 + t;
    if (i > NODES) return;
    if (i == NODES) { rowptr[NODES] = EDGES; return; }
    rowptr[i] = boffb + iscan[i];
}

// ---- graph-pinned 64-row-tile gemm map: blockIdx%8 == owner graph of tile bm ----
__device__ __forceinline__ bool gemm_map64(int i, int& bm, int& bn) {
    int g = i & 7, s = i >> 3;
    int b0 = (6250 * g + 63) >> 6;
    int b1 = (6250 * (g + 1) + 63) >> 6;
    int t = b0 + (s >> 1);
    if (t >= b1) return false;
    bm = t;
    bn = s & 1;
    return true;
}

// ---------------- GEMM body: 64x128 tile, 4 waves, software-pipelined ------------
// Rotation: {bar; write LDS(cur); bar; ISSUE loads(next); ds_read+MFMA(cur)}.
// F32A: A is f32 (the raw x input); converted to bf16 (RNE, bit-identical to the
// old standalone cast) right before the LDS write — kills the 153.6 MB cast pass.
template<bool F32A>
__device__ __forceinline__ void gemm64_body(const void* __restrict__ Aptr,
                                            const u16* __restrict__ Bt,
                                            u16* __restrict__ C,
                                            int K, int bm, int bn,
                                            u16* As, u16* Bs) {
    const int tid  = threadIdx.x;
    const int wave = tid >> 6, lane = tid & 63;
    const int quad = lane >> 4, l16 = lane & 15;
    const int sr = tid >> 2;
    const int sc = tid & 3;
    const int swz = (sc ^ ((sr >> 1) & 3)) * 8;
    const int rphys = (quad ^ ((l16 >> 1) & 3)) * 8;

    int ar = bm * 64 + sr;
    if (F32A && ar > NODES - 1) ar = NODES - 1;   // x sized exactly NODES*CIN; pad
    const float* Agf = (const float*)Aptr + (size_t)ar * K + sc * 8;   // rows clamp
    const u16*   Agh = (const u16*)Aptr + (size_t)(bm * 64 + sr) * K + sc * 8;
    const u16*   Bg  = Bt + (size_t)(bn * 128 + sr) * K + sc * 8;

    f32x4 acc[4][2];
#pragma unroll
    for (int i = 0; i < 4; i++)
#pragma unroll
        for (int j = 0; j < 2; j++) { f32x4 z = {0.f, 0.f, 0.f, 0.f}; acc[i][j] = z; }

    int4   av;
    float4 af0, af1;
    if (F32A) { af0 = *(const float4*)(Agf); af1 = *(const float4*)(Agf + 4); }
    else      { av  = *(const int4*)(Agh); }
    int4 bv0 = *(const int4*)(Bg);
    int4 bv1 = *(const int4*)(Bg + (size_t)64 * K);

    for (int k0 = 0; k0 < K; k0 += 32) {
        int4 avw = F32A ? f32x8_to_bf16x8(af0, af1) : av;
        __syncthreads();
        *(int4*)(As + sr * 32 + swz)        = avw;
        *(int4*)(Bs + sr * 32 + swz)        = bv0;
        *(int4*)(Bs + (sr + 64) * 32 + swz) = bv1;
        __syncthreads();
        if (k0 + 32 < K) {                         // issue next-tile loads early
            if (F32A) {
                af0 = *(const float4*)(Agf + k0 + 32);
                af1 = *(const float4*)(Agf + k0 + 36);
            } else {
                av  = *(const int4*)(Agh + k0 + 32);
            }
            bv0 = *(const int4*)(Bg + k0 + 32);
            bv1 = *(const int4*)(Bg + (size_t)64 * K + k0 + 32);
        }
        bf16x8 af[4], bfr[2];
#pragma unroll
        for (int i = 0; i < 4; i++)
            af[i] = *(const bf16x8*)(As + (i * 16 + l16) * 32 + rphys);
#pragma unroll
        for (int j = 0; j < 2; j++)
            bfr[j] = *(const bf16x8*)(Bs + (wave * 32 + j * 16 + l16) * 32 + rphys);
#pragma unroll
        for (int i = 0; i < 4; i++)
#pragma unroll
            for (int j = 0; j < 2; j++)
                acc[i][j] = __builtin_amdgcn_mfma_f32_16x16x32_bf16(af[i], bfr[j], acc[i][j], 0, 0, 0);
    }

    const int crow0 = bm * 64 + quad * 4;
    const int ccol0 = bn * 128 + wave * 32 + l16;
#pragma unroll
    for (int i = 0; i < 4; i++)
#pragma unroll
        for (int j = 0; j < 2; j++)
#pragma unroll
            for (int r = 0; r < 4; r++)
                C[(size_t)(crow0 + i * 16 + r) * HID + ccol0 + j * 16] = f2bf(acc[i][j][r]);
}

// ---------------- K2: GEMM1 (f32 A, fused cast) + CSR fill merged ----------------
__global__ __launch_bounds__(256) void k2_kernel(
        const float* __restrict__ x, const u16* __restrict__ Wt1, u16* __restrict__ xw,
        const int* __restrict__ ei, const float* __restrict__ ew,
        const float* __restrict__ dinv, const int* __restrict__ rowptr,
        const u32* __restrict__ blockbase, int2* __restrict__ csr) {
    __shared__ __align__(16) char smem[12544];
    int b = blockIdx.x;
    if (b < GEMM_GRID) {
        int bm, bn;
        if (!gemm_map64(b, bm, bn)) return;
        u16* As = (u16*)smem;                       // 4096 B
        u16* Bs = (u16*)(smem + 4096);              // 8192 B
        gemm64_body<true>(x, Wt1, xw, CIN, bm, bn, As, Bs);
    } else {
        u32* cursor = (u32*)smem;                   // 12500 B
        int g  = b & 7;
        int bb = (b - GEMM_GRID) >> 3;              // slice 0..31
        const u32* bbase = blockbase + (size_t)(g * 32 + bb) * NP_G;
        const int* rp = rowptr + g * NP_G;
        int ebase = g * EPG + bb * ESL;
        for (int h = 0; h < 2; ++h) {
            int lo = h * ESL;
            for (int k = threadIdx.x; k < ESL; k += 256)
                cursor[k] = (u32)rp[lo + k] + bbase[lo + k];
            __syncthreads();
#pragma unroll 4
            for (int k = threadIdx.x; k < ESL; k += 256) {
                int e = ebase + k;
                int d = ei[EDGES + e];
                int il = d - g * NP_G - lo;
                if ((unsigned)il < (unsigned)ESL) {
                    int s = ei[e];
                    u32 pos = atomicAdd(&cursor[il], 1u);   // LDS atomic
                    csr[pos] = make_int2(s, __float_as_int(dinv[s] * ew[e] * dinv[d]));
                }
            }
            __syncthreads();
        }
    }
}

// plain GEMM (layers 2,3)
__global__ __launch_bounds__(256) void gemm_bt(const u16* __restrict__ A,
                                               const u16* __restrict__ Bt,
                                               u16* __restrict__ C, int K) {
    __shared__ u16 As[64 * 32];
    __shared__ u16 Bs[128 * 32];
    int bm, bn;
    if (!gemm_map64(blockIdx.x, bm, bn)) return;
    gemm64_body<false>(A, Bt, C, K, bm, bn, As, Bs);
}

// ---------------- aggregation ----------------------------------------------------
// v6 (verified R9): TWO nodes per wave; all shfls execute with full exec (uniform
// guards), half-dependent mask applied as select AFTER the shfl.
template<bool SCORE>
__global__ void agg_kernel(const u16* __restrict__ xw, u16* __restrict__ xo,
                           const int* __restrict__ rowptr, const int2* __restrict__ csr,
                           const float* __restrict__ dinv, const float* __restrict__ bias,
                           const u16* __restrict__ xs1, const u16* __restrict__ xs2,
                           const float* __restrict__ pw, const float* __restrict__ invn,
                           float* __restrict__ score, u64* __restrict__ keys) {
    int wave = threadIdx.x >> 6;
    int lane = threadIdx.x & 63;
    int g  = blockIdx.x & 7;
    int nl = (blockIdx.x >> 3) * 8 + wave * 2;      // first node of the pair
    if (nl >= NP_G) return;                          // nl even: pair never straddles
    int w = g * NP_G + nl;
    int half = lane >> 5;
    int f8 = (lane & 31) * 8;

    float accA[8], accB[8];
#pragma unroll
    for (int j = 0; j < 8; ++j) { accA[j] = 0.f; accB[j] = 0.f; }

    int pA = rowptr[w], pM = rowptr[w + 1], pB = rowptr[w + 2];
    for (int q = pA; q < pB; q += 64) {
        int m = min(64, pB - q);
        int2 e = make_int2(0, 0);
        if (lane < m) e = csr[q + lane];            // one coalesced load, both nodes
        int hA = pM - q; hA = hA < 0 ? 0 : (hA > m ? m : hA);   // A:[0,hA) B:[hA,m)
        int nsA = (hA + 7) >> 3;
        int nsB = (m - hA + 7) >> 3;
        int ns = nsA > nsB ? nsA : nsB;
        for (int s = 0; s < ns; ++s) {
            int jA = s * 8, jB = hA + s * 8;
            bool doA = jA < hA;                     // wave-uniform
            bool doB = jB < m;                      // wave-uniform
            u16x8 vA[4], vB[4];
            float wtA[4], wtB[4];
            if (doA) {                              // uniform guard: full exec inside
                int capA = hA - 1;
#pragma unroll
                for (int k = 0; k < 4; ++k) {
                    int i0 = jA + 2 * k + half;
                    int c0 = min(i0, capA);
                    int   sA = __shfl(e.x, c0, 64);                    // full-exec
                    float wA = __int_as_float(__shfl(e.y, c0, 64));    // full-exec
                    wtA[k] = (i0 <= capA) ? wA : 0.f;                  // select after
                    vA[k] = *(const u16x8*)(xw + (size_t)sA * HID + f8);
                }
            }
            if (doB) {
                int capB = m - 1;
#pragma unroll
                for (int k = 0; k < 4; ++k) {
                    int i0 = jB + 2 * k + half;
                    int c0 = min(i0, capB);
                    int   sB = __shfl(e.x, c0, 64);                    // full-exec
                    float wB = __int_as_float(__shfl(e.y, c0, 64));    // full-exec
                    wtB[k] = (i0 <= capB) ? wB : 0.f;                  // select after
                    vB[k] = *(const u16x8*)(xw + (size_t)sB * HID + f8);
                }
            }
            if (doA) {
#pragma unroll
                for (int k = 0; k < 4; ++k)
#pragma unroll
                    for (int t = 0; t < 8; ++t)
                        accA[t] += wtA[k] * bf2f(vA[k][t]);
            }
            if (doB) {
#pragma unroll
                for (int k = 0; k < 4; ++k)
#pragma unroll
                    for (int t = 0; t < 8; ++t)
                        accB[t] += wtB[k] * bf2f(vB[k][t]);
            }
        }
    }

#pragma unroll
    for (int j = 0; j < 8; ++j) {                   // combine even/odd-edge halves
        accA[j] += __shfl_xor(accA[j], 32, 64);
        accB[j] += __shfl_xor(accB[j], 32, 64);
    }

    int wn = w + half;                               // lane<32 -> A, lane>=32 -> B
    size_t ro = (size_t)wn * HID + f8;
    float di = dinv[wn], sw = di * di;
    u16x8 sv = *(const u16x8*)(xw + ro);
    float bb[8];
    {
        float4 t0 = *(const float4*)(bias + f8);
        float4 t1 = *(const float4*)(bias + f8 + 4);
        bb[0] = t0.x; bb[1] = t0.y; bb[2] = t0.z; bb[3] = t0.w;
        bb[4] = t1.x; bb[5] = t1.y; bb[6] = t1.z; bb[7] = t1.w;
    }
    u16x8 o;
    float ov[8];
#pragma unroll
    for (int j = 0; j < 8; ++j) {
        float as = half ? accB[j] : accA[j];
        float v = fmaxf(as + sw * bf2f(sv[j]) + bb[j], 0.f);
        o[j] = f2bf(v);
        ov[j] = bf2f(o[j]);               // post-rounding value (matches stored x3)
    }
    *(u16x8*)(xo + ro) = o;                          // both halves: distinct rows

    if (SCORE) {
        u16x8 v1 = *(const u16x8*)(xs1 + ro);
        u16x8 v2 = *(const u16x8*)(xs2 + ro);
        float acc = 0.f;
#pragma unroll
        for (int j = 0; j < 8; ++j) {
            acc += bf2f(v1[j]) * pw[f8 + j];
            acc += bf2f(v2[j]) * pw[256 + f8 + j];
            acc += ov[j]       * pw[512 + f8 + j];
        }
#pragma unroll
        for (int off = 1; off < 32; off <<= 1) acc += __shfl_xor(acc, off, 64);
        if ((lane & 31) == 0) {                      // lane 0 -> A, lane 32 -> B
            float s = acc * invn[0];
            float sc = 1.f / (1.f + __expf(-s));
            score[wn] = sc;
            keys[wn] = ((u64)__float_as_uint(sc) << 13)
                     | (unsigned int)(NP_G - 1 - (nl + half));
        }
    }
}

// ---------------- top-K radix select + stable compaction, one block per graph ----
__global__ __launch_bounds__(1024) void selcomp_kernel(
        const u64* __restrict__ keys, const float* __restrict__ score,
        int* __restrict__ selidx, float* __restrict__ selscr) {
    __shared__ u64 kk[NP_G];          // 50 KB
    __shared__ unsigned int hist[4][256];
    __shared__ unsigned int sfx[257];
    __shared__ u64 spref;
    __shared__ unsigned int swant;
    int g = blockIdx.x, t = threadIdx.x;
    const u64* kg = keys + (size_t)g * NP_G;
    for (int i = t; i < NP_G; i += 1024) kk[i] = kg[i];
    if (t == 0) { spref = 0ull; swant = KKEEP; }
    const int wgrp = (t >> 8) & 3;
    u64 mask = 0ull;
    __syncthreads();
    for (int shift = 40; shift >= 0; shift -= 8) {
        if (t < 256) { hist[0][t] = 0; hist[1][t] = 0; hist[2][t] = 0; hist[3][t] = 0; }
        __syncthreads();
        u64 pref = spref;
        for (int i = t; i < NP_G; i += 1024) {
            u64 key = kk[i];
            if ((key & mask) == pref)
                atomicAdd(&hist[wgrp][(unsigned int)(key >> shift) & 255u], 1u);
        }
        __syncthreads();
        if (t < 256) sfx[t] = hist[0][t] + hist[1][t] + hist[2][t] + hist[3][t];
        if (t == 0) sfx[256] = 0;
        __syncthreads();
        for (int off = 1; off < 256; off <<= 1) {
            unsigned int v = 0;
            if (t < 256 && t + off < 256) v = sfx[t + off];
            __syncthreads();
            if (t < 256 && t + off < 256) sfx[t] += v;
            __syncthreads();
        }
        unsigned int want = swant;
        __syncthreads();
        if (t < 256) {
            unsigned int s0 = sfx[t], s1 = sfx[t + 1];
            if (s0 >= want && s1 < want) {
                spref = pref | ((u64)t << shift);
                swant = want - s1;
            }
        }
        __syncthreads();
        mask |= (255ull << shift);
    }
    u64 kth = spref;
    int lane = t & 63, wv = t >> 6;
    __shared__ int wsum[16];
    __shared__ int cbase;
    if (t == 0) cbase = 0;
    __syncthreads();
    for (int k = 0; k < (NP_G + 1023) / 1024; ++k) {
        int i = k * 1024 + t;
        bool sel = (i < NP_G) && (kk[i] >= kth);
        int n = g * NP_G + i;
        u64 bal = __ballot(sel);
        int prefix = __popcll(bal & ((1ull << lane) - 1ull));
        if (lane == 0) wsum[wv] = __popcll(bal);
        __syncthreads();
        if (t == 0) {
            int s = cbase;
            for (int j = 0; j < 16; ++j) { int tmp = wsum[j]; wsum[j] = s; s += tmp; }
            cbase = s;
        }
        __syncthreads();
        if (sel) {
            int pos = wsum[wv] + prefix;
            selidx[g * KKEEP + pos] = n;
            selscr[g * KKEEP + pos] = score[n];
        }
        __syncthreads();
    }
}

// ---------------- readout: branch-free gather over compacted list ----------------
__global__ __launch_bounds__(256) void readout_kernel(
        const u16* __restrict__ x1, const u16* __restrict__ x2,
        const u16* __restrict__ x3,
        const int* __restrict__ selidx, const float* __restrict__ selscr,
        float* __restrict__ sumbuf, int* __restrict__ maxbuf) {
    int g = blockIdx.x, tpart = blockIdx.y, c = blockIdx.z;
    int fcol = threadIdx.x;
    const u16* xt = (tpart == 0) ? x1 : ((tpart == 1) ? x2 : x3);
    __shared__ int   sidx[RCHUNK];
    __shared__ float sscr[RCHUNK];
    int base = g * KKEEP + c * RCHUNK;
    if (fcol < RCHUNK) { sidx[fcol] = selidx[base + fcol]; sscr[fcol] = selscr[base + fcol]; }
    __syncthreads();
    float sum = 0.f, mx = 0.f;
#pragma unroll 1
    for (int j = 0; j < RCHUNK; j += 4) {
        int n0 = sidx[j], n1 = sidx[j + 1], n2 = sidx[j + 2], n3 = sidx[j + 3];
        float s0 = sscr[j], s1 = sscr[j + 1], s2 = sscr[j + 2], s3 = sscr[j + 3];
        float v0 = bf2f(xt[(size_t)n0 * HID + fcol]) * s0;
        float v1 = bf2f(xt[(size_t)n1 * HID + fcol]) * s1;
        float v2 = bf2f(xt[(size_t)n2 * HID + fcol]) * s2;
        float v3 = bf2f(xt[(size_t)n3 * HID + fcol]) * s3;
        sum += v0 + v1 + v2 + v3;
        mx = fmaxf(mx, fmaxf(fmaxf(v0, v1), fmaxf(v2, v3)));
    }
    int o = (g * 3 + tpart) * HID + fcol;
    atomicAdd(&sumbuf[o], sum);
    atomicMax(&maxbuf[o], __float_as_int(mx));
}

// ---------------- MLP layer 1, k-split ----------------
__global__ __launch_bounds__(256) void mlp1_kernel(const float* __restrict__ sumbuf,
                                                   const int* __restrict__ maxbuf,
                                                   const float* __restrict__ lw1,
                                                   float* __restrict__ h1acc) {
    int g = blockIdx.x, ch = blockIdx.y, t = threadIdx.x;
    __shared__ float r[MLPCK];
    int k0 = ch * MLPCK;
    if (t < MLPCK) {
        int i = k0 + t;
        r[t] = (i < 768) ? sumbuf[g * 768 + i] * (1.f / 5000.f)
                         : __int_as_float(maxbuf[g * 768 + (i - 768)]);
    }
    __syncthreads();
    float a0 = 0.f, a1 = 0.f, a2 = 0.f, a3 = 0.f;
#pragma unroll
    for (int i = 0; i < MLPCK; i += 4) {
        a0 += r[i]     * lw1[(size_t)(k0 + i)     * 256 + t];
        a1 += r[i + 1] * lw1[(size_t)(k0 + i + 1) * 256 + t];
        a2 += r[i + 2] * lw1[(size_t)(k0 + i + 2) * 256 + t];
        a3 += r[i + 3] * lw1[(size_t)(k0 + i + 3) * 256 + t];
    }
    atomicAdd(&h1acc[g * 256 + t], (a0 + a1) + (a2 + a3));
}

// ---------------- MLP layers 2+3 ----------------
__global__ __launch_bounds__(256) void mlp2_kernel(const float* __restrict__ h1acc,
                                                   const float* __restrict__ lb1,
                                                   const float* __restrict__ lw2,
                                                   const float* __restrict__ lb2,
                                                   const float* __restrict__ lw3,
                                                   const float* __restrict__ lb3,
                                                   float* __restrict__ out) {
    __shared__ float h1[256];
    __shared__ float part[256];
    __shared__ float h2[128];
    int g = blockIdx.x, t = threadIdx.x;
    h1[t] = fmaxf(h1acc[g * 256 + t] + lb1[t], 0.f);
    __syncthreads();
    int col = t & 127, half = t >> 7;
    float a = 0.f;
#pragma unroll
    for (int i = 0; i < 128; i += 4) {
        int k = half * 128 + i;
        a += h1[k]     * lw2[k * 128 + col]
           + h1[k + 1] * lw2[(k + 1) * 128 + col]
           + h1[k + 2] * lw2[(k + 2) * 128 + col]
           + h1[k + 3] * lw2[(k + 3) * 128 + col];
    }
    part[t] = a;
    __syncthreads();
    if (t < 128) h2[t] = fmaxf(part[t] + part[t + 128] + lb2[t], 0.f);
    __syncthreads();
    if (t < 3) {
        float a3 = lb3[t];
        for (int i = 0; i < 128; ++i) a3 += h2[i] * lw3[i * 3 + t];
        out[g * 3 + t] = a3;
    }
}

extern "C" void kernel_launch(void* const* d_in, const int* in_sizes, int n_in,
                              void* d_out, int out_size, void* d_ws, size_t ws_size,
                              hipStream_t stream) {
    const float* x   = (const float*)d_in[0];
    const int*   ei  = (const int*)d_in[1];
    const float* ew  = (const float*)d_in[2];
    const float* W1  = (const float*)d_in[4];
    const float* b1  = (const float*)d_in[5];
    const float* W2  = (const float*)d_in[6];
    const float* b2  = (const float*)d_in[7];
    const float* pw  = (const float*)d_in[8];
    const float* lw1 = (const float*)d_in[9];
    const float* lb1 = (const float*)d_in[10];
    const float* lw2 = (const float*)d_in[11];
    const float* lb2 = (const float*)d_in[12];
    const float* lw3 = (const float*)d_in[13];
    const float* lb3 = (const float*)d_in[14];
    float* out = (float*)d_out;

    char* p = (char*)d_ws;
    auto alloc = [&](size_t bytes) -> char* {
        char* r = p;
        p += (bytes + 255) & ~(size_t)255;
        return r;
    };
    u16* A0  = (u16*)alloc((size_t)MPAD * CIN * 2);   // x1/x2 live here
    u16* x3  = (u16*)alloc((size_t)MPAD * HID * 2);
    u16* xw  = (u16*)alloc((size_t)MPAD * HID * 2);
    u16* Wt1 = (u16*)alloc((size_t)HID * CIN * 2);
    u16* Wt2 = (u16*)alloc((size_t)HID * HID * 2);
    int2*  csr    = (int2*)alloc((size_t)EDGES * 8);
    u64*   partial   = (u64*)alloc((size_t)256 * NP_G * 8);   // 12.8 MB
    u32*   blockbase = (u32*)alloc((size_t)256 * NP_G * 4);   // 6.4 MB
    int*   rowptr = (int*)alloc((size_t)(NODES + 1) * 4);
    int*   iscan  = (int*)alloc((size_t)NODES * 4);
    int*   bsum   = (int*)alloc((size_t)SCANB * 4);
    u64*   keys   = (u64*)alloc((size_t)NODES * 8);
    float* score  = (float*)alloc((size_t)NODES * 4);
    float* dinv   = (float*)alloc((size_t)NODES * 4);
    int*   selidx = (int*)alloc((size_t)NGRAPH * KKEEP * 4);
    float* selscr = (float*)alloc((size_t)NGRAPH * KKEEP * 4);
    float* invn   = (float*)alloc(256);
    char* zbase = p;                                  // everything below is zero-init
    float* sumbuf = (float*)alloc(6144 * 4);
    int*   maxbuf = (int*)alloc(6144 * 4);
    float* h1acc  = (float*)alloc((size_t)NGRAPH * 256 * 4);
    size_t zbytes = (size_t)(p - zbase);

    u16* x1 = A0;
    u16* x2 = A0 + (size_t)MPAD * HID;

    hipMemsetAsync(zbase, 0, zbytes, stream);

    k1_kernel<<<K1_TOTAL, 256, 0, stream>>>(ei, ew, partial,
                                            W1, W2, pw, Wt1, Wt2, invn);
    scan1_kernel<<<SCANB, 256, 0, stream>>>(partial, blockbase, iscan, bsum, dinv);
    scan3_kernel<<<SCANB + 1, 256, 0, stream>>>(iscan, bsum, rowptr);
    k2_kernel<<<K2_TOTAL, 256, 0, stream>>>(x, Wt1, xw, ei, ew, dinv, rowptr,
                                            blockbase, csr);

    int aggBlocks = 8 * ((NP_G + 7) / 8);   // 2 nodes/wave; graph = blockIdx & 7

    agg_kernel<false><<<aggBlocks, 256, 0, stream>>>(xw, x1, rowptr, csr, dinv, b1,
                                                     nullptr, nullptr, nullptr, nullptr,
                                                     nullptr, nullptr);
    gemm_bt<<<GEMM_GRID, 256, 0, stream>>>(x1, Wt2, xw, HID);
    agg_kernel<false><<<aggBlocks, 256, 0, stream>>>(xw, x2, rowptr, csr, dinv, b2,
                                                     nullptr, nullptr, nullptr, nullptr,
                                                     nullptr, nullptr);
    gemm_bt<<<GEMM_GRID, 256, 0, stream>>>(x2, Wt2, xw, HID);
    agg_kernel<true><<<aggBlocks, 256, 0, stream>>>(xw, x3, rowptr, csr, dinv, b2,
                                                    x1, x2, pw, invn, score, keys);

    selcomp_kernel<<<NGRAPH, 1024, 0, stream>>>(keys, score, selidx, selscr);
    readout_kernel<<<dim3(NGRAPH, 3, KKEEP / RCHUNK), 256, 0, stream>>>(
        x1, x2, x3, selidx, selscr, sumbuf, maxbuf);
    mlp1_kernel<<<dim3(NGRAPH, MLPCH), 256, 0, stream>>>(sumbuf, maxbuf, lw1, h1acc);
    mlp2_kernel<<<NGRAPH, 256, 0, stream>>>(h1acc, lb1, lw2, lb2, lw3, lb3, out);
}

// Round 11
// 442.291 us; speedup vs baseline: 1.0414x; 1.0414x over previous
//
#include <hip/hip_runtime.h>
#include <stdint.h>

#define NODES  50000
#define MPAD   50048      // 391 * 128
#define NGRAPH 8
#define NP_G   6250
#define EPG    100000
#define EDGES  800000
#define KKEEP  5000
#define HID    256
#define CIN    512
#define H3     768
#define SCANB  196        // 196*256 = 50176 >= NODES
#define RCHUNK 200        // KKEEP / 25
#define MLPCH  24         // layer-1 k-chunks
#define MLPCK  64         // 1536 / 24
#define ESL    3125       // edges per slice (EPG/32); also NP_G/2 bucket-half

// K1 block ranges: hist, cast_x, cast_W1, cast_W2, pwnorm
#define K1_HIST  512
#define K1_CAST  25000    // 50000*512/(4*256)
#define K1_W1    512
#define K1_W2    256
#define K1_TOTAL (K1_HIST + K1_CAST + K1_W1 + K1_W2 + 1)
// gemm grid: 64x128 tiles, graph-pinned (blockIdx%8 == owner graph of row-tile).
#define GEMM_GRID 1568
#define FILL_GRID 256     // 8 graphs * 32 slices
#define K2_TOTAL  (GEMM_GRID + FILL_GRID)

using f32x4  = __attribute__((ext_vector_type(4))) float;
using bf16x8 = __attribute__((ext_vector_type(8))) short;
using u16x8  = __attribute__((ext_vector_type(8))) unsigned short;
typedef unsigned short u16;
typedef unsigned int   u32;
typedef unsigned long long u64;

__device__ __forceinline__ float bf2f(u16 u) {
    return __uint_as_float(((uint32_t)u) << 16);
}
__device__ __forceinline__ u16 f2bf(float f) {     // RNE
    uint32_t u = __float_as_uint(f);
    u += 0x7fffu + ((u >> 16) & 1u);
    return (u16)(u >> 16);
}

// ---------------- K1: LDS edge histograms + x cast + W casts + pwnorm ------------
__global__ __launch_bounds__(256) void k1_kernel(
        const int* __restrict__ ei, const float* __restrict__ ew,
        u64* __restrict__ partial,
        const float* __restrict__ x, u16* __restrict__ A0,
        const float* __restrict__ W1, const float* __restrict__ W2,
        const float* __restrict__ pw,
        u16* __restrict__ Wt1, u16* __restrict__ Wt2, float* __restrict__ invn) {
    __shared__ __align__(16) char smem[ESL * 8];   // 25000 B
    int b = blockIdx.x, t = threadIdx.x;
    if (b < K1_HIST) {
        u64* hl = (u64*)smem;                       // 3125 buckets (one half)
        int g  = b >> 6;
        int r  = b & 63;
        int bb = r >> 1;                            // edge slice 0..31
        int h  = r & 1;                             // bucket half
        for (int k = t; k < ESL; k += 256) hl[k] = 0ull;
        __syncthreads();
        int ebase = g * EPG + bb * ESL;
        int lo = h * ESL;
        for (int k = t; k < ESL; k += 256) {
            int e = ebase + k;
            int d = ei[EDGES + e];
            int il = d - g * NP_G - lo;
            if ((unsigned)il < (unsigned)ESL) {
                u64 enc = (1ull << 48) | (u64)(ew[e] * 4294967296.0f);
                atomicAdd(&hl[il], enc);            // LDS atomic
            }
        }
        __syncthreads();
        u64* prow = partial + (size_t)(g * 32 + bb) * NP_G + lo;
        for (int k = t; k < ESL; k += 256) prow[k] = hl[k];
    } else if (b < K1_HIST + K1_CAST) {             // cast x -> bf16 (real rows)
        size_t base = ((size_t)(b - K1_HIST) * 256 + t) * 4;
        float4 v = *(const float4*)(x + base);
        ushort4 o;
        o.x = f2bf(v.x); o.y = f2bf(v.y); o.z = f2bf(v.z); o.w = f2bf(v.w);
        *(ushort4*)(A0 + base) = o;
    } else if (b < K1_HIST + K1_CAST + K1_W1) {     // Wt1[n*512+k] = W1[k*256+n]
        int id = (b - K1_HIST - K1_CAST) * 256 + t;
        int n = id >> 9, k = id & 511;
        Wt1[id] = f2bf(W1[(size_t)k * HID + n]);
    } else if (b < K1_TOTAL - 1) {                  // Wt2[n*256+k] = W2[k*256+n]
        int id = (b - K1_HIST - K1_CAST - K1_W1) * 256 + t;
        int n = id >> 8, k = id & 255;
        Wt2[id] = f2bf(W2[(size_t)k * HID + n]);
    } else {                                        // pwnorm
        float* sh = (float*)smem;
        float s = 0.f;
        for (int i = t; i < H3; i += 256) { float v = pw[i]; s += v * v; }
        sh[t] = s; __syncthreads();
        for (int off = 128; off; off >>= 1) {
            if (t < off) sh[t] += sh[t + off];
            __syncthreads();
        }
        if (t == 0) invn[0] = rsqrtf(sh[0]);
    }
}

// ---- scan1 v2: reduce 32 partials/node -> count + deg; emit per-block prefixes ---
__global__ void scan1_kernel(const u64* __restrict__ partial,
                             u32* __restrict__ blockbase,
                             int* __restrict__ iscan, int* __restrict__ bsum,
                             float* __restrict__ dinv) {
    int b = blockIdx.x, t = threadIdx.x;
    int i = b * 256 + t;
    int c = 0;
    if (i < NODES) {
        int g = i / NP_G, il = i - g * NP_G;
        size_t base = (size_t)(g * 32) * NP_G + il;
        u64 fix = 0ull; u32 cnt = 0;
#pragma unroll 4
        for (int j = 0; j < 32; ++j) {
            size_t idx = base + (size_t)j * NP_G;
            u64 pv = partial[idx];
            blockbase[idx] = cnt;                 // exclusive prefix over blocks
            cnt += (u32)(pv >> 48);
            fix += pv & 0xFFFFFFFFFFFFull;
        }
        c = (int)cnt;
        float deg = (float)fix * (1.0f / 4294967296.0f);
        dinv[i] = rsqrtf(deg + 1.0f);
    }
    int lane = t & 63, wv = t >> 6;
    int v = c;
    for (int off = 1; off < 64; off <<= 1) {
        int u = __shfl_up(v, off);
        if (lane >= off) v += u;
    }
    __shared__ int ws[4];
    if (lane == 63) ws[wv] = v;
    __syncthreads();
    if (t == 0) { int s = 0; for (int k = 0; k < 4; k++) { int tmp = ws[k]; ws[k] = s; s += tmp; } }
    __syncthreads();
    v += ws[wv];
    if (i < NODES) iscan[i] = v - c;              // block-local EXCLUSIVE scan
    if (t == 255) bsum[b] = v;
}

// scan3 (scan2 fused): each block reduces bsum[0..b-1] itself, then adds iscan.
__global__ void scan3_kernel(const int* __restrict__ iscan, const int* __restrict__ bsum,
                             int* __restrict__ rowptr) {
    int b = blockIdx.x, t = threadIdx.x;
    int v = (t < b) ? bsum[t] : 0;                // b <= 196 < 256, no SCANB overrun
    for (int off = 1; off < 64; off <<= 1) v += __shfl_xor(v, off, 64);
    __shared__ int ws[4];
    if ((t & 63) == 0) ws[t >> 6] = v;
    __syncthreads();
    int boffb = ws[0] + ws[1] + ws[2] + ws[3];
    int i = b * 256 + t;
    if (i > NODES) return;
    if (i == NODES) { rowptr[NODES] = EDGES; return; }
    rowptr[i] = boffb + iscan[i];
}

// ---- graph-pinned 64-row-tile gemm map: blockIdx%8 == owner graph of tile bm ----
__device__ __forceinline__ bool gemm_map64(int i, int& bm, int& bn) {
    int g = i & 7, s = i >> 3;
    int b0 = (6250 * g + 63) >> 6;
    int b1 = (6250 * (g + 1) + 63) >> 6;
    int t = b0 + (s >> 1);
    if (t >= b1) return false;
    bm = t;
    bn = s & 1;
    return true;
}

// ---------------- GEMM body: 64x128 tile, 4 waves, software-pipelined ------------
// Rotation: {bar; write LDS(cur); bar; ISSUE loads(next); ds_read+MFMA(cur)}.
__device__ __forceinline__ void gemm64_body(const u16* __restrict__ A,
                                            const u16* __restrict__ Bt,
                                            u16* __restrict__ C,
                                            int K, int bm, int bn,
                                            u16* As, u16* Bs) {
    const int tid  = threadIdx.x;
    const int wave = tid >> 6, lane = tid & 63;
    const int quad = lane >> 4, l16 = lane & 15;
    const int sr = tid >> 2;
    const int sc = tid & 3;
    const int swz = (sc ^ ((sr >> 1) & 3)) * 8;
    const int rphys = (quad ^ ((l16 >> 1) & 3)) * 8;

    const u16* Ag = A + (size_t)(bm * 64 + sr) * K + sc * 8;
    const u16* Bg = Bt + (size_t)(bn * 128 + sr) * K + sc * 8;

    f32x4 acc[4][2];
#pragma unroll
    for (int i = 0; i < 4; i++)
#pragma unroll
        for (int j = 0; j < 2; j++) { f32x4 z = {0.f, 0.f, 0.f, 0.f}; acc[i][j] = z; }

    int4 av  = *(const int4*)(Ag);
    int4 bv0 = *(const int4*)(Bg);
    int4 bv1 = *(const int4*)(Bg + (size_t)64 * K);

    for (int k0 = 0; k0 < K; k0 += 32) {
        __syncthreads();
        *(int4*)(As + sr * 32 + swz)        = av;
        *(int4*)(Bs + sr * 32 + swz)        = bv0;
        *(int4*)(Bs + (sr + 64) * 32 + swz) = bv1;
        __syncthreads();
        if (k0 + 32 < K) {                         // issue next-tile loads early
            av  = *(const int4*)(Ag + k0 + 32);
            bv0 = *(const int4*)(Bg + k0 + 32);
            bv1 = *(const int4*)(Bg + (size_t)64 * K + k0 + 32);
        }
        bf16x8 af[4], bfr[2];
#pragma unroll
        for (int i = 0; i < 4; i++)
            af[i] = *(const bf16x8*)(As + (i * 16 + l16) * 32 + rphys);
#pragma unroll
        for (int j = 0; j < 2; j++)
            bfr[j] = *(const bf16x8*)(Bs + (wave * 32 + j * 16 + l16) * 32 + rphys);
#pragma unroll
        for (int i = 0; i < 4; i++)
#pragma unroll
            for (int j = 0; j < 2; j++)
                acc[i][j] = __builtin_amdgcn_mfma_f32_16x16x32_bf16(af[i], bfr[j], acc[i][j], 0, 0, 0);
    }

    const int crow0 = bm * 64 + quad * 4;
    const int ccol0 = bn * 128 + wave * 32 + l16;
#pragma unroll
    for (int i = 0; i < 4; i++)
#pragma unroll
        for (int j = 0; j < 2; j++)
#pragma unroll
            for (int r = 0; r < 4; r++)
                C[(size_t)(crow0 + i * 16 + r) * HID + ccol0 + j * 16] = f2bf(acc[i][j][r]);
}

// ---------------- K2: GEMM1 + CSR fill merged (independent work, overlapped) -----
__global__ __launch_bounds__(256) void k2_kernel(
        const u16* __restrict__ A0, const u16* __restrict__ Wt1, u16* __restrict__ xw,
        const int* __restrict__ ei, const float* __restrict__ ew,
        const float* __restrict__ dinv, const int* __restrict__ rowptr,
        const u32* __restrict__ blockbase, int2* __restrict__ csr) {
    __shared__ __align__(16) char smem[12544];
    int b = blockIdx.x;
    if (b < GEMM_GRID) {
        int bm, bn;
        if (!gemm_map64(b, bm, bn)) return;
        u16* As = (u16*)smem;                       // 4096 B
        u16* Bs = (u16*)(smem + 4096);              // 8192 B
        gemm64_body(A0, Wt1, xw, CIN, bm, bn, As, Bs);
    } else {
        u32* cursor = (u32*)smem;                   // 12500 B
        int g  = b & 7;
        int bb = (b - GEMM_GRID) >> 3;              // slice 0..31
        const u32* bbase = blockbase + (size_t)(g * 32 + bb) * NP_G;
        const int* rp = rowptr + g * NP_G;
        int ebase = g * EPG + bb * ESL;
        for (int h = 0; h < 2; ++h) {
            int lo = h * ESL;
            for (int k = threadIdx.x; k < ESL; k += 256)
                cursor[k] = (u32)rp[lo + k] + bbase[lo + k];
            __syncthreads();
#pragma unroll 4
            for (int k = threadIdx.x; k < ESL; k += 256) {
                int e = ebase + k;
                int d = ei[EDGES + e];
                int il = d - g * NP_G - lo;
                if ((unsigned)il < (unsigned)ESL) {
                    int s = ei[e];
                    u32 pos = atomicAdd(&cursor[il], 1u);   // LDS atomic
                    csr[pos] = make_int2(s, __float_as_int(dinv[s] * ew[e] * dinv[d]));
                }
            }
            __syncthreads();
        }
    }
}

// plain GEMM (layers 2,3)
__global__ __launch_bounds__(256) void gemm_bt(const u16* __restrict__ A,
                                               const u16* __restrict__ Bt,
                                               u16* __restrict__ C, int K) {
    __shared__ u16 As[64 * 32];
    __shared__ u16 Bs[128 * 32];
    int bm, bn;
    if (!gemm_map64(blockIdx.x, bm, bn)) return;
    gemm64_body(A, Bt, C, K, bm, bn, As, Bs);
}

// ---------------- aggregation ----------------------------------------------------
// v6 (verified R9): TWO nodes per wave; all shfls execute with full exec (uniform
// guards), half-dependent mask applied as select AFTER the shfl.
template<bool SCORE>
__global__ void agg_kernel(const u16* __restrict__ xw, u16* __restrict__ xo,
                           const int* __restrict__ rowptr, const int2* __restrict__ csr,
                           const float* __restrict__ dinv, const float* __restrict__ bias,
                           const u16* __restrict__ xs1, const u16* __restrict__ xs2,
                           const float* __restrict__ pw, const float* __restrict__ invn,
                           float* __restrict__ score, u64* __restrict__ keys) {
    int wave = threadIdx.x >> 6;
    int lane = threadIdx.x & 63;
    int g  = blockIdx.x & 7;
    int nl = (blockIdx.x >> 3) * 8 + wave * 2;      // first node of the pair
    if (nl >= NP_G) return;                          // nl even: pair never straddles
    int w = g * NP_G + nl;
    int half = lane >> 5;
    int f8 = (lane & 31) * 8;

    float accA[8], accB[8];
#pragma unroll
    for (int j = 0; j < 8; ++j) { accA[j] = 0.f; accB[j] = 0.f; }

    int pA = rowptr[w], pM = rowptr[w + 1], pB = rowptr[w + 2];
    for (int q = pA; q < pB; q += 64) {
        int m = min(64, pB - q);
        int2 e = make_int2(0, 0);
        if (lane < m) e = csr[q + lane];            // one coalesced load, both nodes
        int hA = pM - q; hA = hA < 0 ? 0 : (hA > m ? m : hA);   // A:[0,hA) B:[hA,m)
        int nsA = (hA + 7) >> 3;
        int nsB = (m - hA + 7) >> 3;
        int ns = nsA > nsB ? nsA : nsB;
        for (int s = 0; s < ns; ++s) {
            int jA = s * 8, jB = hA + s * 8;
            bool doA = jA < hA;                     // wave-uniform
            bool doB = jB < m;                      // wave-uniform
            u16x8 vA[4], vB[4];
            float wtA[4], wtB[4];
            if (doA) {                              // uniform guard: full exec inside
                int capA = hA - 1;
#pragma unroll
                for (int k = 0; k < 4; ++k) {
                    int i0 = jA + 2 * k + half;
                    int c0 = min(i0, capA);
                    int   sA = __shfl(e.x, c0, 64);                    // full-exec
                    float wA = __int_as_float(__shfl(e.y, c0, 64));    // full-exec
                    wtA[k] = (i0 <= capA) ? wA : 0.f;                  // select after
                    vA[k] = *(const u16x8*)(xw + (size_t)sA * HID + f8);
                }
            }
            if (doB) {
                int capB = m - 1;
#pragma unroll
                for (int k = 0; k < 4; ++k) {
                    int i0 = jB + 2 * k + half;
                    int c0 = min(i0, capB);
                    int   sB = __shfl(e.x, c0, 64);                    // full-exec
                    float wB = __int_as_float(__shfl(e.y, c0, 64));    // full-exec
                    wtB[k] = (i0 <= capB) ? wB : 0.f;                  // select after
                    vB[k] = *(const u16x8*)(xw + (size_t)sB * HID + f8);
                }
            }
            if (doA) {
#pragma unroll
                for (int k = 0; k < 4; ++k)
#pragma unroll
                    for (int t = 0; t < 8; ++t)
                        accA[t] += wtA[k] * bf2f(vA[k][t]);
            }
            if (doB) {
#pragma unroll
                for (int k = 0; k < 4; ++k)
#pragma unroll
                    for (int t = 0; t < 8; ++t)
                        accB[t] += wtB[k] * bf2f(vB[k][t]);
            }
        }
    }

#pragma unroll
    for (int j = 0; j < 8; ++j) {                   // combine even/odd-edge halves
        accA[j] += __shfl_xor(accA[j], 32, 64);
        accB[j] += __shfl_xor(accB[j], 32, 64);
    }

    int wn = w + half;                               // lane<32 -> A, lane>=32 -> B
    size_t ro = (size_t)wn * HID + f8;
    float di = dinv[wn], sw = di * di;
    u16x8 sv = *(const u16x8*)(xw + ro);
    float bb[8];
    {
        float4 t0 = *(const float4*)(bias + f8);
        float4 t1 = *(const float4*)(bias + f8 + 4);
        bb[0] = t0.x; bb[1] = t0.y; bb[2] = t0.z; bb[3] = t0.w;
        bb[4] = t1.x; bb[5] = t1.y; bb[6] = t1.z; bb[7] = t1.w;
    }
    u16x8 o;
    float ov[8];
#pragma unroll
    for (int j = 0; j < 8; ++j) {
        float as = half ? accB[j] : accA[j];
        float v = fmaxf(as + sw * bf2f(sv[j]) + bb[j], 0.f);
        o[j] = f2bf(v);
        ov[j] = bf2f(o[j]);               // post-rounding value (matches stored x3)
    }
    *(u16x8*)(xo + ro) = o;                          // both halves: distinct rows

    if (SCORE) {
        u16x8 v1 = *(const u16x8*)(xs1 + ro);
        u16x8 v2 = *(const u16x8*)(xs2 + ro);
        float acc = 0.f;
#pragma unroll
        for (int j = 0; j < 8; ++j) {
            acc += bf2f(v1[j]) * pw[f8 + j];
            acc += bf2f(v2[j]) * pw[256 + f8 + j];
            acc += ov[j]       * pw[512 + f8 + j];
        }
#pragma unroll
        for (int off = 1; off < 32; off <<= 1) acc += __shfl_xor(acc, off, 64);
        if ((lane & 31) == 0) {                      // lane 0 -> A, lane 32 -> B
            float s = acc * invn[0];
            float sc = 1.f / (1.f + __expf(-s));
            score[wn] = sc;
            keys[wn] = ((u64)__float_as_uint(sc) << 13)
                     | (unsigned int)(NP_G - 1 - (nl + half));
        }
    }
}

// ---------------- top-K radix select + stable compaction, one block per graph ----
// v2: per-pass suffix scan done by a SINGLE WAVE via shfl (no ladder barriers):
// lane L owns hist entries 4L..4L+3; wave shfl_down suffix-scan gives sfx; the
// boundary bucket is found in-lane. 3 barriers/pass vs ~21 (saves ~108 barriers
// of 1024 threads across 6 passes). Selection arithmetic bit-identical.
__global__ __launch_bounds__(1024) void selcomp_kernel(
        const u64* __restrict__ keys, const float* __restrict__ score,
        int* __restrict__ selidx, float* __restrict__ selscr) {
    __shared__ u64 kk[NP_G];          // 50 KB
    __shared__ unsigned int hist[4][256];
    __shared__ u64 spref;
    __shared__ unsigned int swant;
    int g = blockIdx.x, t = threadIdx.x;
    const u64* kg = keys + (size_t)g * NP_G;
    for (int i = t; i < NP_G; i += 1024) kk[i] = kg[i];
    if (t == 0) { spref = 0ull; swant = KKEEP; }
    const int wgrp = (t >> 8) & 3;
    u64 mask = 0ull;
    __syncthreads();
    for (int shift = 40; shift >= 0; shift -= 8) {
        if (t < 256) { hist[0][t] = 0; hist[1][t] = 0; hist[2][t] = 0; hist[3][t] = 0; }
        __syncthreads();
        u64 pref = spref;
        unsigned want = swant;                      // stable: written last pass, barrier since
        for (int i = t; i < NP_G; i += 1024) {
            u64 key = kk[i];
            if ((key & mask) == pref)
                atomicAdd(&hist[wgrp][(unsigned int)(key >> shift) & 255u], 1u);
        }
        __syncthreads();
        if (t < 64) {                               // single-wave suffix scan
            int L = t;
            unsigned e0 = hist[0][4*L+0] + hist[1][4*L+0] + hist[2][4*L+0] + hist[3][4*L+0];
            unsigned e1 = hist[0][4*L+1] + hist[1][4*L+1] + hist[2][4*L+1] + hist[3][4*L+1];
            unsigned e2 = hist[0][4*L+2] + hist[1][4*L+2] + hist[2][4*L+2] + hist[3][4*L+2];
            unsigned e3 = hist[0][4*L+3] + hist[1][4*L+3] + hist[2][4*L+3] + hist[3][4*L+3];
            unsigned latot = e0 + e1 + e2 + e3;
            unsigned v = latot;
            for (int off = 1; off < 64; off <<= 1) {
                unsigned u = __shfl_down(v, off, 64);
                if (L + off < 64) v += u;           // v = suffix incl. own lane
            }
            unsigned s0 = v;                        // sfx[4L+0]
            unsigned s1 = s0 - e0;                  // sfx[4L+1]
            unsigned s2 = s1 - e1;                  // sfx[4L+2]
            unsigned s3 = s2 - e2;                  // sfx[4L+3]
            unsigned s4 = s3 - e3;                  // sfx[4L+4] (= next lane's s0)
            if (s0 >= want && s1 < want) { spref = pref | ((u64)(4*L+0) << shift); swant = want - s1; }
            else if (s1 >= want && s2 < want) { spref = pref | ((u64)(4*L+1) << shift); swant = want - s2; }
            else if (s2 >= want && s3 < want) { spref = pref | ((u64)(4*L+2) << shift); swant = want - s3; }
            else if (s3 >= want && s4 < want) { spref = pref | ((u64)(4*L+3) << shift); swant = want - s4; }
        }
        __syncthreads();
        mask |= (255ull << shift);
    }
    u64 kth = spref;
    int lane = t & 63, wv = t >> 6;
    __shared__ int wsum[16];
    __shared__ int cbase;
    if (t == 0) cbase = 0;
    __syncthreads();
    for (int k = 0; k < (NP_G + 1023) / 1024; ++k) {
        int i = k * 1024 + t;
        bool sel = (i < NP_G) && (kk[i] >= kth);
        int n = g * NP_G + i;
        u64 bal = __ballot(sel);
        int prefix = __popcll(bal & ((1ull << lane) - 1ull));
        if (lane == 0) wsum[wv] = __popcll(bal);
        __syncthreads();
        if (t == 0) {
            int s = cbase;
            for (int j = 0; j < 16; ++j) { int tmp = wsum[j]; wsum[j] = s; s += tmp; }
            cbase = s;
        }
        __syncthreads();
        if (sel) {
            int pos = wsum[wv] + prefix;
            selidx[g * KKEEP + pos] = n;
            selscr[g * KKEEP + pos] = score[n];
        }
        __syncthreads();
    }
}

// ---------------- readout: branch-free gather over compacted list ----------------
__global__ __launch_bounds__(256) void readout_kernel(
        const u16* __restrict__ x1, const u16* __restrict__ x2,
        const u16* __restrict__ x3,
        const int* __restrict__ selidx, const float* __restrict__ selscr,
        float* __restrict__ sumbuf, int* __restrict__ maxbuf) {
    int g = blockIdx.x, tpart = blockIdx.y, c = blockIdx.z;
    int fcol = threadIdx.x;
    const u16* xt = (tpart == 0) ? x1 : ((tpart == 1) ? x2 : x3);
    __shared__ int   sidx[RCHUNK];
    __shared__ float sscr[RCHUNK];
    int base = g * KKEEP + c * RCHUNK;
    if (fcol < RCHUNK) { sidx[fcol] = selidx[base + fcol]; sscr[fcol] = selscr[base + fcol]; }
    __syncthreads();
    float sum = 0.f, mx = 0.f;
#pragma unroll 1
    for (int j = 0; j < RCHUNK; j += 4) {
        int n0 = sidx[j], n1 = sidx[j + 1], n2 = sidx[j + 2], n3 = sidx[j + 3];
        float s0 = sscr[j], s1 = sscr[j + 1], s2 = sscr[j + 2], s3 = sscr[j + 3];
        float v0 = bf2f(xt[(size_t)n0 * HID + fcol]) * s0;
        float v1 = bf2f(xt[(size_t)n1 * HID + fcol]) * s1;
        float v2 = bf2f(xt[(size_t)n2 * HID + fcol]) * s2;
        float v3 = bf2f(xt[(size_t)n3 * HID + fcol]) * s3;
        sum += v0 + v1 + v2 + v3;
        mx = fmaxf(mx, fmaxf(fmaxf(v0, v1), fmaxf(v2, v3)));
    }
    int o = (g * 3 + tpart) * HID + fcol;
    atomicAdd(&sumbuf[o], sum);
    atomicMax(&maxbuf[o], __float_as_int(mx));
}

// ---------------- MLP layer 1, k-split ----------------
__global__ __launch_bounds__(256) void mlp1_kernel(const float* __restrict__ sumbuf,
                                                   const int* __restrict__ maxbuf,
                                                   const float* __restrict__ lw1,
                                                   float* __restrict__ h1acc) {
    int g = blockIdx.x, ch = blockIdx.y, t = threadIdx.x;
    __shared__ float r[MLPCK];
    int k0 = ch * MLPCK;
    if (t < MLPCK) {
        int i = k0 + t;
        r[t] = (i < 768) ? sumbuf[g * 768 + i] * (1.f / 5000.f)
                         : __int_as_float(maxbuf[g * 768 + (i - 768)]);
    }
    __syncthreads();
    float a0 = 0.f, a1 = 0.f, a2 = 0.f, a3 = 0.f;
#pragma unroll
    for (int i = 0; i < MLPCK; i += 4) {
        a0 += r[i]     * lw1[(size_t)(k0 + i)     * 256 + t];
        a1 += r[i + 1] * lw1[(size_t)(k0 + i + 1) * 256 + t];
        a2 += r[i + 2] * lw1[(size_t)(k0 + i + 2) * 256 + t];
        a3 += r[i + 3] * lw1[(size_t)(k0 + i + 3) * 256 + t];
    }
    atomicAdd(&h1acc[g * 256 + t], (a0 + a1) + (a2 + a3));
}

// ---------------- MLP layers 2+3 ----------------
__global__ __launch_bounds__(256) void mlp2_kernel(const float* __restrict__ h1acc,
                                                   const float* __restrict__ lb1,
                                                   const float* __restrict__ lw2,
                                                   const float* __restrict__ lb2,
                                                   const float* __restrict__ lw3,
                                                   const float* __restrict__ lb3,
                                                   float* __restrict__ out) {
    __shared__ float h1[256];
    __shared__ float part[256];
    __shared__ float h2[128];
    int g = blockIdx.x, t = threadIdx.x;
    h1[t] = fmaxf(h1acc[g * 256 + t] + lb1[t], 0.f);
    __syncthreads();
    int col = t & 127, half = t >> 7;
    float a = 0.f;
#pragma unroll
    for (int i = 0; i < 128; i += 4) {
        int k = half * 128 + i;
        a += h1[k]     * lw2[k * 128 + col]
           + h1[k + 1] * lw2[(k + 1) * 128 + col]
           + h1[k + 2] * lw2[(k + 2) * 128 + col]
           + h1[k + 3] * lw2[(k + 3) * 128 + col];
    }
    part[t] = a;
    __syncthreads();
    if (t < 128) h2[t] = fmaxf(part[t] + part[t + 128] + lb2[t], 0.f);
    __syncthreads();
    if (t < 3) {
        float a3 = lb3[t];
        for (int i = 0; i < 128; ++i) a3 += h2[i] * lw3[i * 3 + t];
        out[g * 3 + t] = a3;
    }
}

extern "C" void kernel_launch(void* const* d_in, const int* in_sizes, int n_in,
                              void* d_out, int out_size, void* d_ws, size_t ws_size,
                              hipStream_t stream) {
    const float* x   = (const float*)d_in[0];
    const int*   ei  = (const int*)d_in[1];
    const float* ew  = (const float*)d_in[2];
    const float* W1  = (const float*)d_in[4];
    const float* b1  = (const float*)d_in[5];
    const float* W2  = (const float*)d_in[6];
    const float* b2  = (const float*)d_in[7];
    const float* pw  = (const float*)d_in[8];
    const float* lw1 = (const float*)d_in[9];
    const float* lb1 = (const float*)d_in[10];
    const float* lw2 = (const float*)d_in[11];
    const float* lb2 = (const float*)d_in[12];
    const float* lw3 = (const float*)d_in[13];
    const float* lb3 = (const float*)d_in[14];
    float* out = (float*)d_out;

    char* p = (char*)d_ws;
    auto alloc = [&](size_t bytes) -> char* {
        char* r = p;
        p += (bytes + 255) & ~(size_t)255;
        return r;
    };
    u16* A0  = (u16*)alloc((size_t)MPAD * CIN * 2);   // x bf16; x1/x2 alias after GEMM1
    u16* x3  = (u16*)alloc((size_t)MPAD * HID * 2);
    u16* xw  = (u16*)alloc((size_t)MPAD * HID * 2);
    u16* Wt1 = (u16*)alloc((size_t)HID * CIN * 2);
    u16* Wt2 = (u16*)alloc((size_t)HID * HID * 2);
    int2*  csr    = (int2*)alloc((size_t)EDGES * 8);
    u64*   partial   = (u64*)alloc((size_t)256 * NP_G * 8);   // 12.8 MB
    u32*   blockbase = (u32*)alloc((size_t)256 * NP_G * 4);   // 6.4 MB
    int*   rowptr = (int*)alloc((size_t)(NODES + 1) * 4);
    int*   iscan  = (int*)alloc((size_t)NODES * 4);
    int*   bsum   = (int*)alloc((size_t)SCANB * 4);
    u64*   keys   = (u64*)alloc((size_t)NODES * 8);
    float* score  = (float*)alloc((size_t)NODES * 4);
    float* dinv   = (float*)alloc((size_t)NODES * 4);
    int*   selidx = (int*)alloc((size_t)NGRAPH * KKEEP * 4);
    float* selscr = (float*)alloc((size_t)NGRAPH * KKEEP * 4);
    float* invn   = (float*)alloc(256);
    char* zbase = p;                                  // everything below is zero-init
    float* sumbuf = (float*)alloc(6144 * 4);
    int*   maxbuf = (int*)alloc(6144 * 4);
    float* h1acc  = (float*)alloc((size_t)NGRAPH * 256 * 4);
    size_t zbytes = (size_t)(p - zbase);

    u16* x1 = A0;                         // reuse A0 after GEMM1 consumed it
    u16* x2 = A0 + (size_t)MPAD * HID;

    hipMemsetAsync(zbase, 0, zbytes, stream);

    k1_kernel<<<K1_TOTAL, 256, 0, stream>>>(ei, ew, partial, x, A0,
                                            W1, W2, pw, Wt1, Wt2, invn);
    scan1_kernel<<<SCANB, 256, 0, stream>>>(partial, blockbase, iscan, bsum, dinv);
    scan3_kernel<<<SCANB + 1, 256, 0, stream>>>(iscan, bsum, rowptr);
    k2_kernel<<<K2_TOTAL, 256, 0, stream>>>(A0, Wt1, xw, ei, ew, dinv, rowptr,
                                            blockbase, csr);

    int aggBlocks = 8 * ((NP_G + 7) / 8);   // 2 nodes/wave; graph = blockIdx & 7

    agg_kernel<false><<<aggBlocks, 256, 0, stream>>>(xw, x1, rowptr, csr, dinv, b1,
                                                     nullptr, nullptr, nullptr, nullptr,
                                                     nullptr, nullptr);
    gemm_bt<<<GEMM_GRID, 256, 0, stream>>>(x1, Wt2, xw, HID);
    agg_kernel<false><<<aggBlocks, 256, 0, stream>>>(xw, x2, rowptr, csr, dinv, b2,
                                                     nullptr, nullptr, nullptr, nullptr,
                                                     nullptr, nullptr);
    gemm_bt<<<GEMM_GRID, 256, 0, stream>>>(x2, Wt2, xw, HID);
    agg_kernel<true><<<aggBlocks, 256, 0, stream>>>(xw, x3, rowptr, csr, dinv, b2,
                                                    x1, x2, pw, invn, score, keys);

    selcomp_kernel<<<NGRAPH, 1024, 0, stream>>>(keys, score, selidx, selscr);
    readout_kernel<<<dim3(NGRAPH, 3, KKEEP / RCHUNK), 256, 0, stream>>>(
        x1, x2, x3, selidx, selscr, sumbuf, maxbuf);
    mlp1_kernel<<<dim3(NGRAPH, MLPCH), 256, 0, stream>>>(sumbuf, maxbuf, lw1, h1acc);
    mlp2_kernel<<<NGRAPH, 256, 0, stream>>>(h1acc, lb1, lw2, lb2, lw3, lb3, out);
}